// Round 11
// baseline (116.882 us; speedup 1.0000x reference)
//
#include <hip/hip_runtime.h>
#include <stdint.h>

#define LOG2E 1.4426950408889634f

typedef __attribute__((ext_vector_type(8))) __bf16 bf16x8;
typedef __attribute__((ext_vector_type(4))) __bf16 bf16x4;
typedef __attribute__((ext_vector_type(4))) float f32x4;

__device__ inline void gll16(const void* g, void* l) {
  __builtin_amdgcn_global_load_lds(
      (const __attribute__((address_space(1))) void*)g,
      (__attribute__((address_space(3))) void*)l, 16, 0, 0);
}

// ---------------- fp32 -> bf16 conversion (all 5 tensors, one launch) ----------------
__global__ __launch_bounds__(256) void cvt_all(
    const float* __restrict__ hs, const float* __restrict__ wq,
    const float* __restrict__ wk, const float* __restrict__ wv,
    const float* __restrict__ wo,
    __bf16* __restrict__ hsb, __bf16* __restrict__ wqb, __bf16* __restrict__ wkb,
    __bf16* __restrict__ wvb, __bf16* __restrict__ wob) {
  int bid = blockIdx.x;
  const float* s; __bf16* d; int i;
  if (bid < 4096) { s = hs; d = hsb; i = bid * 256 + threadIdx.x; }
  else {
    int seg = (bid - 4096) >> 10;
    i = ((bid - 4096) & 1023) * 256 + threadIdx.x;
    s = seg == 0 ? wq : seg == 1 ? wk : seg == 2 ? wv : wo;
    d = seg == 0 ? wqb : seg == 1 ? wkb : seg == 2 ? wvb : wob;
  }
  float4 v = ((const float4*)s)[i];
  bf16x4 o;
  o[0] = (__bf16)v.x; o[1] = (__bf16)v.y; o[2] = (__bf16)v.z; o[3] = (__bf16)v.w;
  *(bf16x4*)&d[(size_t)i * 4] = o;
}

// ---------------- merged QKV projection GEMM ----------------
#define KSCALE 0.18033688011112042f  // HD^-0.5 * log2(e)
__global__ __launch_bounds__(256, 3) void qkv_gemm(
    const __bf16* __restrict__ hsb, const __bf16* __restrict__ wqb,
    const __bf16* __restrict__ wkb, const __bf16* __restrict__ wvb,
    __bf16* __restrict__ qbuf, __bf16* __restrict__ kbuf,
    __bf16* __restrict__ vtb) {
  constexpr int K = 1024;
  __shared__ __align__(16) __bf16 lta[128 * 32];
  __shared__ __align__(16) __bf16 ltb[128 * 32];
  const int bid = blockIdx.x;
  const int z = bid >> 8, r = bid & 255;
  const __bf16 *A, *Bt;
  int m0, n0;
  if (z < 2) {
    A = hsb; Bt = z ? wkb : wqb;
    m0 = (r & 31) * 128; n0 = (r >> 5) * 128;
  } else {
    A = wvb; Bt = hsb;
    m0 = (r & 7) * 128; n0 = (r >> 3) * 128;
  }
  const int tid = threadIdx.x;
  const int w = tid >> 6, l = tid & 63;
  const int lg = l >> 4, lr = l & 15;
  const int wm = (w >> 1) * 64, wn = (w & 1) * 64;
  f32x4 acc[4][4] = {};
  const int srow = w * 16 + (l >> 2);
  const int scol = (l & 3) * 8;
  const __bf16* ga = A + (size_t)(m0 + srow) * K + scol;
  const __bf16* gb = Bt + (size_t)(n0 + srow) * K + scol;
  __bf16* la = &lta[(size_t)w * 16 * 32];
  __bf16* lb = &ltb[(size_t)w * 16 * 32];
  for (int k0 = 0; k0 < K; k0 += 32) {
    __syncthreads();
    gll16(ga + k0, la);
    gll16(ga + 64 * K + k0, la + 64 * 32);
    gll16(gb + k0, lb);
    gll16(gb + 64 * K + k0, lb + 64 * 32);
    __syncthreads();
    bf16x8 af[4], bfr[4];
#pragma unroll
    for (int i = 0; i < 4; ++i) {
      af[i]  = *(const bf16x8*)&lta[(wm + i * 16 + lr) * 32 + lg * 8];
      bfr[i] = *(const bf16x8*)&ltb[(wn + i * 16 + lr) * 32 + lg * 8];
    }
#pragma unroll
    for (int i = 0; i < 4; ++i)
#pragma unroll
      for (int j = 0; j < 4; ++j)
        acc[i][j] = __builtin_amdgcn_mfma_f32_16x16x32_bf16(af[i], bfr[j], acc[i][j], 0, 0, 0);
  }
#pragma unroll
  for (int i = 0; i < 4; ++i)
#pragma unroll
    for (int j = 0; j < 4; ++j)
#pragma unroll
      for (int rr = 0; rr < 4; ++rr) {
        int gm = m0 + wm + i * 16 + lg * 4 + rr;
        int gn = n0 + wn + j * 16 + lr;
        float v = acc[i][j][rr];
        if (z < 2) {
          int bb = gm >> 11, s = gm & 2047, hh = gn >> 6, d = gn & 63;
          __bf16* dst = z ? kbuf : qbuf;
          if (z) v *= KSCALE;
          dst[(((size_t)bb * 16 + hh) * 2048 + s) * 64 + d] = (__bf16)v;
        } else {
          int bb = gn >> 11, s = gn & 2047, hh = gm >> 6, d = gm & 63;
          vtb[(((size_t)bb * 16 + hh) * 64 + d) * 2048 + s] = (__bf16)v;
        }
      }
}

// ---------------- output GEMM: 128x64 tiles -> 512 blocks (2/CU) ----------------
__global__ __launch_bounds__(256, 2) void gemm_out(const __bf16* __restrict__ A,
                                                   const __bf16* __restrict__ Bt,
                                                   float* __restrict__ C,
                                                   int M, int N) {
  constexpr int K = 1024;
  __shared__ __align__(16) __bf16 lta[128 * 32];
  __shared__ __align__(16) __bf16 ltb[64 * 32];
  const int tid = threadIdx.x;
  const int w = tid >> 6, l = tid & 63;
  const int lg = l >> 4, lr = l & 15;
  const int m0 = blockIdx.x * 128, n0 = blockIdx.y * 64;
  const int wm = (w >> 1) * 64, wn = (w & 1) * 32;
  f32x4 acc[4][2] = {};
  const int srow = tid >> 2;          // 0..63
  const int scol = (tid & 3) * 8;
  const __bf16* ga = A + (size_t)(m0 + srow) * K + scol;
  const __bf16* gb = Bt + (size_t)(n0 + srow) * K + scol;
  __bf16* la = &lta[(size_t)w * 512];
  __bf16* lb = &ltb[(size_t)w * 512];
  for (int k0 = 0; k0 < K; k0 += 32) {
    __syncthreads();
    gll16(ga + k0, la);
    gll16(ga + (size_t)64 * K + k0, la + 64 * 32);
    gll16(gb + k0, lb);
    __syncthreads();
    bf16x8 af[4], bfr[2];
#pragma unroll
    for (int i = 0; i < 4; ++i)
      af[i]  = *(const bf16x8*)&lta[(wm + i * 16 + lr) * 32 + lg * 8];
#pragma unroll
    for (int j = 0; j < 2; ++j)
      bfr[j] = *(const bf16x8*)&ltb[(wn + j * 16 + lr) * 32 + lg * 8];
#pragma unroll
    for (int i = 0; i < 4; ++i)
#pragma unroll
      for (int j = 0; j < 2; ++j)
        acc[i][j] = __builtin_amdgcn_mfma_f32_16x16x32_bf16(af[i], bfr[j], acc[i][j], 0, 0, 0);
  }
#pragma unroll
  for (int i = 0; i < 4; ++i)
#pragma unroll
    for (int j = 0; j < 2; ++j)
#pragma unroll
      for (int rr = 0; rr < 4; ++rr) {
        int gm = m0 + wm + i * 16 + lg * 4 + rr;
        int gn = n0 + wn + j * 16 + lr;
        C[(size_t)gm * N + gn] = acc[i][j][rr];
      }
}

// ---------------- attention (split-K over KV for long blocks) ----------------
// 1536 blocks: idx = bx>>5, bh = bx&31.
//   idx <  32: SPLIT block — t = 31-(idx>>1) in 31..16, half = idx&1.
//              half0: KV tiles [0,cA), half1: [cA,ntt). Writes partial
//              (O bf16, m/l f32) to pOb/pML, no epilogue. Max 8 iters.
//   idx >= 32: UNSPLIT — t = 47-idx in 15..0, full range + epilogue. <=8 iters.
// 4 waves x 16 q-rows, swapped QK^T, exp2-domain softmax (K pre-scaled),
// XOR-swizzled LDS, pre-swizzled-source global_load_lds staging, pure-VALU
// P redistribution (cvt_pk + permlane32/16_swap). LDS 32 KB -> 5 blocks/CU.
#define DEFER_THR 11.5f
#define SWZ(row, col) (((row) << 7) + ((col) ^ (((row) & 7) << 3)))   // stride 128
#define SWZK(row, col) (((row) << 6) + ((col) ^ (((row) & 7) << 3)))  // stride 64

__global__ __launch_bounds__(256, 5) void attn_kernel(
    const __bf16* __restrict__ qb,    // [32][2048][64]
    const __bf16* __restrict__ kb,    // [32][2048][64] (pre-scaled)
    const __bf16* __restrict__ vtb,   // [32][64][2048]
    const float* __restrict__ memory, // [16][64][64]
    const float* __restrict__ memnorm,// [16][64]
    const float* __restrict__ beta,   // [16]
    __bf16* __restrict__ comb,        // [4096][1024]
    __bf16* __restrict__ pOb,         // [1024][64][64] partial O
    float* __restrict__ pML)          // [1024][128] partial m,l
{
  __shared__ __align__(16) __bf16 kt[128 * 64];   // 16 KB (reused as mt)
  __shared__ __align__(16) __bf16 vt[64 * 128];   // 16 KB  -> 32 KB total

  const int tid = threadIdx.x;
  const int w = tid >> 6, l = tid & 63;
  const int lg = l >> 4, lr = l & 15;
  const int idx = blockIdx.x >> 5;
  const int bh = blockIdx.x & 31;
  const int hh = bh & 15, b = bh >> 4;
  const bool split = idx < 32;
  const int t = split ? (31 - (idx >> 1)) : (47 - idx);
  const int half = split ? (idx & 1) : 0;
  const int wq0 = t * 64 + w * 16;
  const int ntt = (t >> 1) + 1;            // total KV128 tiles
  const int cA = (ntt + 1) >> 1;
  const int kvb = (split && half) ? cA : 0;
  const int nloc = split ? (half ? ntt - cA : cA) : ntt;

  // staging: pre-swizzled global source columns, linear LDS dest.
  const int k_row = tid >> 3;                          // 0..31
  const int k_col = ((tid & 7) ^ (k_row & 7)) * 8;
  const __bf16* ksrc = kb + ((size_t)bh * 2048 + k_row) * 64 + k_col;
  const int v_d = tid >> 4;                            // 0..15
  const int v_col = ((tid & 15) ^ (v_d & 7)) * 8;
  const __bf16* vsrc = vtb + ((size_t)bh * 64 + v_d) * 2048 + v_col;
  __bf16* kdst = &kt[w * 512];
  __bf16* vdst = &vt[w * 512];

  // ---- Q fragments (per-lane: row/col = lr, k = kk*32 + lg*8 + j) ----
  bf16x8 qf[2];
#pragma unroll
  for (int kk = 0; kk < 2; ++kk)
    qf[kk] = *(const bf16x8*)(qb + ((size_t)bh * 2048 + wq0 + lr) * 64 + kk * 32 + lg * 8);

  float mrun = -1e30f, lsum = 0.f;
  f32x4 apv[4] = {};

  for (int kv = 0; kv < nloc; ++kv) {
    const int kvg = kvb + kv;
    const int kv0 = kvg * 128;
    __syncthreads();
#pragma unroll
    for (int i = 0; i < 4; ++i) {
      gll16(ksrc + (size_t)(kv0 + i * 32) * 64, kdst + i * 2048);
      gll16(vsrc + (size_t)i * 16 * 2048 + kv0, vdst + i * 2048);
    }
    __syncthreads();   // drains vmcnt -> tiles ready

    // ---- QK^T swapped: sc[nf]: k = kv0+nf*16+lg*4+r, q = wq0+lr ----
    f32x4 sc[8] = {};
#pragma unroll
    for (int kk = 0; kk < 2; ++kk)
#pragma unroll
      for (int nf = 0; nf < 8; ++nf) {
        bf16x8 kf = *(const bf16x8*)&kt[SWZK(nf * 16 + lr, kk * 32 + lg * 8)];
        sc[nf] = __builtin_amdgcn_mfma_f32_16x16x32_bf16(kf, qf[kk], sc[nf], 0, 0, 0);
      }

    // ---- causal mask (global diagonal tile only) ----
    const int qrow = wq0 + lr;
    if (kvg == ntt - 1) {
#pragma unroll
      for (int nf = 0; nf < 8; ++nf)
#pragma unroll
        for (int r = 0; r < 4; ++r)
          if (kv0 + nf * 16 + lg * 4 + r > qrow) sc[nf][r] = -1e30f;
    }

    // ---- in-lane max + 2-shuffle reduce ----
    f32x4 m4 = sc[0];
#pragma unroll
    for (int nf = 1; nf < 8; ++nf)
#pragma unroll
      for (int r = 0; r < 4; ++r) m4[r] = fmaxf(m4[r], sc[nf][r]);
    float mx = fmaxf(fmaxf(m4[0], m4[1]), fmaxf(m4[2], m4[3]));
    mx = fmaxf(mx, __shfl_xor(mx, 16, 64));
    mx = fmaxf(mx, __shfl_xor(mx, 32, 64));

    // ---- defer-max rescale ----
    if (!__all(mx - mrun <= DEFER_THR)) {
      float mold = mrun;
      float mn = fmaxf(mold, mx);
      mrun = mn;
      float scl = __builtin_amdgcn_exp2f(mold - mn);
      lsum *= scl;
      float sclq[4];
#pragma unroll
      for (int r = 0; r < 4; ++r) sclq[r] = __shfl(scl, (lg << 2) | r, 16);
#pragma unroll
      for (int nf = 0; nf < 4; ++nf)
#pragma unroll
        for (int r = 0; r < 4; ++r) apv[nf][r] *= sclq[r];
    }

    // ---- P = exp2(S - m) in place + row-sum ----
    f32x4 rs4 = {0.f, 0.f, 0.f, 0.f};
#pragma unroll
    for (int nf = 0; nf < 8; ++nf)
#pragma unroll
      for (int r = 0; r < 4; ++r) {
        float pv = __builtin_amdgcn_exp2f(sc[nf][r] - mrun);
        sc[nf][r] = pv;
        rs4[r] += pv;
      }
    float rs = (rs4[0] + rs4[1]) + (rs4[2] + rs4[3]);
    rs += __shfl_xor(rs, 16, 64);
    rs += __shfl_xor(rs, 32, 64);
    lsum += rs;

    // ---- in-register P redistribution (pure VALU) + PV ----
#pragma unroll
    for (int kk = 0; kk < 4; ++kk) {
      uint32_t a0, a1, b0, b1;
      asm("v_cvt_pk_bf16_f32 %0, %1, %2" : "=v"(a0) : "v"(sc[2 * kk][0]), "v"(sc[2 * kk][1]));
      asm("v_cvt_pk_bf16_f32 %0, %1, %2" : "=v"(a1) : "v"(sc[2 * kk][2]), "v"(sc[2 * kk][3]));
      asm("v_cvt_pk_bf16_f32 %0, %1, %2" : "=v"(b0) : "v"(sc[2 * kk + 1][0]), "v"(sc[2 * kk + 1][1]));
      asm("v_cvt_pk_bf16_f32 %0, %1, %2" : "=v"(b1) : "v"(sc[2 * kk + 1][2]), "v"(sc[2 * kk + 1][3]));
      asm("v_permlane32_swap_b32 %0, %1" : "+v"(a0), "+v"(b0));
      asm("v_permlane32_swap_b32 %0, %1" : "+v"(a1), "+v"(b1));
      asm("v_permlane16_swap_b32 %0, %1" : "+v"(a0), "+v"(b0));
      asm("v_permlane16_swap_b32 %0, %1" : "+v"(a1), "+v"(b1));
      union { uint32_t u[4]; bf16x8 v; } pa;
      pa.u[0] = a0; pa.u[1] = a1; pa.u[2] = b0; pa.u[3] = b1;
#pragma unroll
      for (int nf = 0; nf < 4; ++nf) {
        bf16x8 vf = *(const bf16x8*)&vt[SWZ(nf * 16 + lr, kk * 32 + lg * 8)];
        apv[nf] = __builtin_amdgcn_mfma_f32_16x16x32_bf16(pa.v, vf, apv[nf], 0, 0, 0);
      }
    }
  }

  // ---- SPLIT epilogue: dump partial state, done ----
  if (split) {
    const int u = idx * 32 + bh;
    __bf16* po = pOb + (size_t)u * 4096;
    float* pml = pML + (size_t)u * 128;
#pragma unroll
    for (int nf = 0; nf < 4; ++nf)
#pragma unroll
      for (int r = 0; r < 4; ++r)
        po[(w * 16 + lg * 4 + r) * 64 + nf * 16 + lr] = (__bf16)apv[nf][r];
    pml[w * 16 + lr] = mrun;
    pml[64 + w * 16 + lr] = lsum;
    return;
  }

  // ---- UNSPLIT epilogue: memory term + combine + write ----
  __syncthreads();
  __bf16* mt = kt;  // reuse kt region for memory^T [80][72]
  for (int i = tid; i < 64 * 64; i += 256) {
    int d = i >> 6, e = i & 63;
    mt[e * 72 + d] = (__bf16)memory[((size_t)hh * 64 + d) * 64 + e];
  }
  for (int i = tid; i < 16 * 64; i += 256) {
    int e = 64 + (i >> 6), d = i & 63;
    mt[e * 72 + d] = (__bf16)memnorm[hh * 64 + d];
  }
  __syncthreads();

  bf16x8 sf[2];
#pragma unroll
  for (int kk = 0; kk < 2; ++kk) {
    bf16x8 q = qf[kk], s;
#pragma unroll
    for (int j = 0; j < 8; ++j) {
      float x = (float)q[j];
      float sg = x > 0.f ? x + 1.f : __builtin_amdgcn_exp2f(x * LOG2E);
      s[j] = (__bf16)sg;
    }
    sf[kk] = s;
  }

  f32x4 am[5] = {};
#pragma unroll
  for (int kk = 0; kk < 2; ++kk)
#pragma unroll
    for (int nf = 0; nf < 5; ++nf) {
      bf16x8 bb = *(const bf16x8*)&mt[(nf * 16 + lr) * 72 + kk * 32 + lg * 8];
      am[nf] = __builtin_amdgcn_mfma_f32_16x16x32_bf16(sf[kk], bb, am[nf], 0, 0, 0);
    }

  const float gate = 1.f / (1.f + __builtin_amdgcn_exp2f(-beta[hh] * LOG2E));
  const float og = 1.f - gate;
  float lsq[4];
#pragma unroll
  for (int r = 0; r < 4; ++r) lsq[r] = __shfl(lsum, (lg << 2) | r, 16);
#pragma unroll
  for (int r = 0; r < 4; ++r) {
    int row = wq0 + lg * 4 + r;
    float linv = __builtin_amdgcn_rcpf(lsq[r]);
    float nrm = fmaxf(am[4][r], 1e-6f);
    float ninv = __builtin_amdgcn_rcpf(nrm);
    size_t base = ((size_t)b * 2048 + row) * 1024 + hh * 64;
#pragma unroll
    for (int nf = 0; nf < 4; ++nf) {
      float al = apv[nf][r] * linv;
      float amv = am[nf][r] * ninv;
      comb[base + nf * 16 + lr] = (__bf16)(gate * amv + og * al);
    }
  }
}

// ---------------- merge kernel: flash-merge split halves + epilogue ----------------
// 512 blocks: tt = bx>>5 (t = 31-tt in 31..16), bh = bx&31.
__global__ __launch_bounds__(256, 2) void attn_merge(
    const __bf16* __restrict__ qb, const __bf16* __restrict__ pOb,
    const float* __restrict__ pML, const float* __restrict__ memory,
    const float* __restrict__ memnorm, const float* __restrict__ beta,
    __bf16* __restrict__ comb) {
  __shared__ __align__(16) __bf16 mt[80 * 72];   // 11.5 KB
  const int tid = threadIdx.x;
  const int w = tid >> 6, l = tid & 63;
  const int lg = l >> 4, lr = l & 15;
  const int tt = blockIdx.x >> 5;
  const int t = 31 - tt;
  const int bh = blockIdx.x & 31;
  const int hh = bh & 15, b = bh >> 4;
  const int wq0 = t * 64 + w * 16;
  const int u0 = (tt * 2) * 32 + bh;
  const int u1 = (tt * 2 + 1) * 32 + bh;

  // stage memory^T + norm rows
  for (int i = tid; i < 64 * 64; i += 256) {
    int d = i >> 6, e = i & 63;
    mt[e * 72 + d] = (__bf16)memory[((size_t)hh * 64 + d) * 64 + e];
  }
  for (int i = tid; i < 16 * 64; i += 256) {
    int e = 64 + (i >> 6), d = i & 63;
    mt[e * 72 + d] = (__bf16)memnorm[hh * 64 + d];
  }

  // per-lane merge scalars (q-row = lr within this wave's 16 rows)
  float m1 = pML[(size_t)u0 * 128 + w * 16 + lr];
  float l1 = pML[(size_t)u0 * 128 + 64 + w * 16 + lr];
  float m2 = pML[(size_t)u1 * 128 + w * 16 + lr];
  float l2 = pML[(size_t)u1 * 128 + 64 + w * 16 + lr];
  float fm = fmaxf(m1, m2);
  float f1 = __builtin_amdgcn_exp2f(m1 - fm);
  float f2 = __builtin_amdgcn_exp2f(m2 - fm);
  float lm = f1 * l1 + f2 * l2;

  // Q fragments + sigma
  bf16x8 qf[2], sf[2];
#pragma unroll
  for (int kk = 0; kk < 2; ++kk) {
    qf[kk] = *(const bf16x8*)(qb + ((size_t)bh * 2048 + wq0 + lr) * 64 + kk * 32 + lg * 8);
    bf16x8 q = qf[kk], s;
#pragma unroll
    for (int j = 0; j < 8; ++j) {
      float x = (float)q[j];
      float sg = x > 0.f ? x + 1.f : __builtin_amdgcn_exp2f(x * LOG2E);
      s[j] = (__bf16)sg;
    }
    sf[kk] = s;
  }
  __syncthreads();

  f32x4 am[5] = {};
#pragma unroll
  for (int kk = 0; kk < 2; ++kk)
#pragma unroll
    for (int nf = 0; nf < 5; ++nf) {
      bf16x8 bb = *(const bf16x8*)&mt[(nf * 16 + lr) * 72 + kk * 32 + lg * 8];
      am[nf] = __builtin_amdgcn_mfma_f32_16x16x32_bf16(sf[kk], bb, am[nf], 0, 0, 0);
    }

  const float gate = 1.f / (1.f + __builtin_amdgcn_exp2f(-beta[hh] * LOG2E));
  const float og = 1.f - gate;
  float lq[4], f1q[4], f2q[4];
#pragma unroll
  for (int r = 0; r < 4; ++r) {
    lq[r]  = __shfl(lm, (lg << 2) | r, 16);
    f1q[r] = __shfl(f1, (lg << 2) | r, 16);
    f2q[r] = __shfl(f2, (lg << 2) | r, 16);
  }
  const __bf16* po0 = pOb + (size_t)u0 * 4096;
  const __bf16* po1 = pOb + (size_t)u1 * 4096;
#pragma unroll
  for (int r = 0; r < 4; ++r) {
    int row = wq0 + lg * 4 + r;
    float linv = __builtin_amdgcn_rcpf(lq[r]);
    float nrm = fmaxf(am[4][r], 1e-6f);
    float ninv = __builtin_amdgcn_rcpf(nrm);
    size_t base = ((size_t)b * 2048 + row) * 1024 + hh * 64;
#pragma unroll
    for (int nf = 0; nf < 4; ++nf) {
      int off = (w * 16 + lg * 4 + r) * 64 + nf * 16 + lr;
      float o = f1q[r] * (float)po0[off] + f2q[r] * (float)po1[off];
      comb[base + nf * 16 + lr] = (__bf16)(gate * am[nf][r] * ninv + og * o * linv);
    }
  }
}

// ---------------- launch ----------------
extern "C" void kernel_launch(void* const* d_in, const int* in_sizes, int n_in,
                              void* d_out, int out_size, void* d_ws, size_t ws_size,
                              hipStream_t stream) {
  const float* hs      = (const float*)d_in[0];
  const float* wq      = (const float*)d_in[1];
  const float* wk      = (const float*)d_in[2];
  const float* wv      = (const float*)d_in[3];
  const float* wo      = (const float*)d_in[4];
  const float* beta    = (const float*)d_in[5];
  const float* memory  = (const float*)d_in[6];
  const float* memnorm = (const float*)d_in[7];
  float* out = (float*)d_out;

  char* ws = (char*)d_ws;
  __bf16* hsb  = (__bf16*)(ws);                        // 8 MB  [4096][1024]
  __bf16* wqb  = (__bf16*)(ws + ((size_t)8  << 20));   // 2 MB
  __bf16* wkb  = (__bf16*)(ws + ((size_t)10 << 20));   // 2 MB
  __bf16* wvb  = (__bf16*)(ws + ((size_t)12 << 20));   // 2 MB
  __bf16* wob  = (__bf16*)(ws + ((size_t)14 << 20));   // 2 MB
  __bf16* qbuf = (__bf16*)(ws + ((size_t)16 << 20));   // 8 MB  [32][2048][64]
  __bf16* kbuf = (__bf16*)(ws + ((size_t)24 << 20));   // 8 MB
  __bf16* vtb  = (__bf16*)(ws + ((size_t)32 << 20));   // 8 MB  [32][64][2048]
  __bf16* comb = (__bf16*)(ws + ((size_t)40 << 20));   // 8 MB  [4096][1024]
  // partial buffers overlay the DEAD hsb/wqb region (qkv_gemm finished first):
  __bf16* pOb  = (__bf16*)(ws);                        // 8 MB  [1024][64][64]
  float*  pML  = (float*)(ws + ((size_t)8 << 20));     // 512 KB [1024][128]

  cvt_all<<<8192, 256, 0, stream>>>(hs, wq, wk, wv, wo, hsb, wqb, wkb, wvb, wob);

  qkv_gemm<<<768, 256, 0, stream>>>(hsb, wqb, wkb, wvb, qbuf, kbuf, vtb);

  attn_kernel<<<1536, 256, 0, stream>>>(qbuf, kbuf, vtb, memory, memnorm, beta,
                                        comb, pOb, pML);

  attn_merge<<<512, 256, 0, stream>>>(qbuf, pOb, pML, memory, memnorm, beta, comb);

  gemm_out<<<dim3(32, 16), 256, 0, stream>>>(comb, wob, out, 4096, 1024);
}

// Round 12
// 100.742 us; speedup vs baseline: 1.1602x; 1.1602x over previous
//
#include <hip/hip_runtime.h>
#include <stdint.h>

#define LOG2E 1.4426950408889634f

typedef __attribute__((ext_vector_type(8))) __bf16 bf16x8;
typedef __attribute__((ext_vector_type(4))) __bf16 bf16x4;
typedef __attribute__((ext_vector_type(4))) float f32x4;

__device__ inline void gll16(const void* g, void* l) {
  __builtin_amdgcn_global_load_lds(
      (const __attribute__((address_space(1))) void*)g,
      (__attribute__((address_space(3))) void*)l, 16, 0, 0);
}

// ---------------- fp32 -> bf16 conversion (all 5 tensors, one launch) ----------------
__global__ __launch_bounds__(256) void cvt_all(
    const float* __restrict__ hs, const float* __restrict__ wq,
    const float* __restrict__ wk, const float* __restrict__ wv,
    const float* __restrict__ wo,
    __bf16* __restrict__ hsb, __bf16* __restrict__ wqb, __bf16* __restrict__ wkb,
    __bf16* __restrict__ wvb, __bf16* __restrict__ wob) {
  int bid = blockIdx.x;
  const float* s; __bf16* d; int i;
  if (bid < 4096) { s = hs; d = hsb; i = bid * 256 + threadIdx.x; }
  else {
    int seg = (bid - 4096) >> 10;
    i = ((bid - 4096) & 1023) * 256 + threadIdx.x;
    s = seg == 0 ? wq : seg == 1 ? wk : seg == 2 ? wv : wo;
    d = seg == 0 ? wqb : seg == 1 ? wkb : seg == 2 ? wvb : wob;
  }
  float4 v = ((const float4*)s)[i];
  bf16x4 o;
  o[0] = (__bf16)v.x; o[1] = (__bf16)v.y; o[2] = (__bf16)v.z; o[3] = (__bf16)v.w;
  *(bf16x4*)&d[(size_t)i * 4] = o;
}

// ---------------- merged QKV projection GEMM (BK=64, XOR-swizzled LDS) ----------------
// 768 blocks, 3/CU. z = bid>>8: z=0 Q, z=1 K (pre-scaled), z=2 V^T.
// LDS tiles [128][64] with elem = row*64 + (col ^ ((row&7)<<3)); staged via
// global_load_lds with pre-swizzled per-thread source column (attn-proven
// pattern). 16 K-steps of BK=64 -> half the barrier/drain count of BK=32.
#define KSCALE 0.18033688011112042f  // HD^-0.5 * log2(e)
#define QSWZ(row, col) (((row) << 6) + ((col) ^ (((row) & 7) << 3)))

__global__ __launch_bounds__(256, 3) void qkv_gemm(
    const __bf16* __restrict__ hsb, const __bf16* __restrict__ wqb,
    const __bf16* __restrict__ wkb, const __bf16* __restrict__ wvb,
    __bf16* __restrict__ qbuf, __bf16* __restrict__ kbuf,
    __bf16* __restrict__ vtb) {
  constexpr int K = 1024;
  __shared__ __align__(16) __bf16 lta[128 * 64];   // 16 KB
  __shared__ __align__(16) __bf16 ltb[128 * 64];   // 16 KB
  const int bid = blockIdx.x;
  const int z = bid >> 8, r = bid & 255;
  const __bf16 *A, *Bt;
  int m0, n0;
  if (z < 2) {
    A = hsb; Bt = z ? wkb : wqb;
    m0 = (r & 31) * 128; n0 = (r >> 5) * 128;
  } else {
    A = wvb; Bt = hsb;
    m0 = (r & 7) * 128; n0 = (r >> 3) * 128;
  }
  const int tid = threadIdx.x;
  const int w = tid >> 6, l = tid & 63;
  const int lg = l >> 4, lr = l & 15;
  const int wm = (w >> 1) * 64, wn = (w & 1) * 64;
  f32x4 acc[4][4] = {};
  // staging: chunk c = p*256 + tid -> row = p*32 + (tid>>3); source col8
  // pre-swizzled: (tid&7) ^ (row&7) = (tid&7) ^ ((tid>>3)&7)  (p*32 ≡ 0 mod 8)
  const int srow = tid >> 3;                               // 0..31
  const int scol = ((tid & 7) ^ ((tid >> 3) & 7)) * 8;
  const __bf16* ga = A + (size_t)(m0 + srow) * K + scol;
  const __bf16* gb = Bt + (size_t)(n0 + srow) * K + scol;
  for (int k0 = 0; k0 < K; k0 += 64) {
    __syncthreads();
#pragma unroll
    for (int p = 0; p < 4; ++p) {
      gll16(ga + (size_t)p * 32 * K + k0, &lta[p * 2048 + w * 512]);
      gll16(gb + (size_t)p * 32 * K + k0, &ltb[p * 2048 + w * 512]);
    }
    __syncthreads();
#pragma unroll
    for (int kk = 0; kk < 2; ++kk) {
      bf16x8 af[4], bfr[4];
#pragma unroll
      for (int i = 0; i < 4; ++i) {
        af[i]  = *(const bf16x8*)&lta[QSWZ(wm + i * 16 + lr, kk * 32 + lg * 8)];
        bfr[i] = *(const bf16x8*)&ltb[QSWZ(wn + i * 16 + lr, kk * 32 + lg * 8)];
      }
#pragma unroll
      for (int i = 0; i < 4; ++i)
#pragma unroll
        for (int j = 0; j < 4; ++j)
          acc[i][j] = __builtin_amdgcn_mfma_f32_16x16x32_bf16(af[i], bfr[j], acc[i][j], 0, 0, 0);
    }
  }
#pragma unroll
  for (int i = 0; i < 4; ++i)
#pragma unroll
    for (int j = 0; j < 4; ++j)
#pragma unroll
      for (int rr = 0; rr < 4; ++rr) {
        int gm = m0 + wm + i * 16 + lg * 4 + rr;
        int gn = n0 + wn + j * 16 + lr;
        float v = acc[i][j][rr];
        if (z < 2) {
          int bb = gm >> 11, s = gm & 2047, hh = gn >> 6, d = gn & 63;
          __bf16* dst = z ? kbuf : qbuf;
          if (z) v *= KSCALE;
          dst[(((size_t)bb * 16 + hh) * 2048 + s) * 64 + d] = (__bf16)v;
        } else {
          int bb = gn >> 11, s = gn & 2047, hh = gm >> 6, d = gm & 63;
          vtb[(((size_t)bb * 16 + hh) * 64 + d) * 2048 + s] = (__bf16)v;
        }
      }
}

// ---------------- output GEMM: 128x64 tiles, 512 blocks, 4/CU ----------------
__global__ __launch_bounds__(256, 4) void gemm_out(const __bf16* __restrict__ A,
                                                   const __bf16* __restrict__ Bt,
                                                   float* __restrict__ C,
                                                   int M, int N) {
  constexpr int K = 1024;
  __shared__ __align__(16) __bf16 lta[128 * 32];
  __shared__ __align__(16) __bf16 ltb[64 * 32];
  const int tid = threadIdx.x;
  const int w = tid >> 6, l = tid & 63;
  const int lg = l >> 4, lr = l & 15;
  const int m0 = blockIdx.x * 128, n0 = blockIdx.y * 64;
  const int wm = (w >> 1) * 64, wn = (w & 1) * 32;
  f32x4 acc[4][2] = {};
  const int srow = tid >> 2;          // 0..63
  const int scol = (tid & 3) * 8;
  const __bf16* ga = A + (size_t)(m0 + srow) * K + scol;
  const __bf16* gb = Bt + (size_t)(n0 + srow) * K + scol;
  __bf16* la = &lta[(size_t)w * 512];
  __bf16* lb = &ltb[(size_t)w * 512];
  for (int k0 = 0; k0 < K; k0 += 32) {
    __syncthreads();
    gll16(ga + k0, la);
    gll16(ga + (size_t)64 * K + k0, la + 64 * 32);
    gll16(gb + k0, lb);
    __syncthreads();
    bf16x8 af[4], bfr[2];
#pragma unroll
    for (int i = 0; i < 4; ++i)
      af[i]  = *(const bf16x8*)&lta[(wm + i * 16 + lr) * 32 + lg * 8];
#pragma unroll
    for (int j = 0; j < 2; ++j)
      bfr[j] = *(const bf16x8*)&ltb[(wn + j * 16 + lr) * 32 + lg * 8];
#pragma unroll
    for (int i = 0; i < 4; ++i)
#pragma unroll
      for (int j = 0; j < 2; ++j)
        acc[i][j] = __builtin_amdgcn_mfma_f32_16x16x32_bf16(af[i], bfr[j], acc[i][j], 0, 0, 0);
  }
#pragma unroll
  for (int i = 0; i < 4; ++i)
#pragma unroll
    for (int j = 0; j < 2; ++j)
#pragma unroll
      for (int rr = 0; rr < 4; ++rr) {
        int gm = m0 + wm + i * 16 + lg * 4 + rr;
        int gn = n0 + wn + j * 16 + lr;
        C[(size_t)gm * N + gn] = acc[i][j][rr];
      }
}

// ---------------- attention + memory retrieval (R10 + setprio) ----------------
#define DEFER_THR 11.5f
#define SWZ(row, col) (((row) << 7) + ((col) ^ (((row) & 7) << 3)))   // stride 128
#define SWZK(row, col) (((row) << 6) + ((col) ^ (((row) & 7) << 3)))  // stride 64

__global__ __launch_bounds__(256, 5) void attn_kernel(
    const __bf16* __restrict__ qb,    // [32][2048][64]
    const __bf16* __restrict__ kb,    // [32][2048][64] (pre-scaled)
    const __bf16* __restrict__ vtb,   // [32][64][2048]
    const float* __restrict__ memory, // [16][64][64]
    const float* __restrict__ memnorm,// [16][64]
    const float* __restrict__ beta,   // [16]
    __bf16* __restrict__ comb)        // [4096][1024]
{
  __shared__ __align__(16) __bf16 kt[128 * 64];   // 16 KB (reused as mt)
  __shared__ __align__(16) __bf16 vt[64 * 128];   // 16 KB  -> 32 KB total

  const int tid = threadIdx.x;
  const int w = tid >> 6, l = tid & 63;
  const int lg = l >> 4, lr = l & 15;
  const int t = 31 - (blockIdx.x >> 5);
  const int bh = blockIdx.x & 31;
  const int hh = bh & 15, b = bh >> 4;
  const int wq0 = t * 64 + w * 16;
  const int ntiles = (t >> 1) + 1;

  const int k_row = tid >> 3;                          // 0..31
  const int k_col = ((tid & 7) ^ (k_row & 7)) * 8;
  const __bf16* ksrc = kb + ((size_t)bh * 2048 + k_row) * 64 + k_col;
  const int v_d = tid >> 4;                            // 0..15
  const int v_col = ((tid & 15) ^ (v_d & 7)) * 8;
  const __bf16* vsrc = vtb + ((size_t)bh * 64 + v_d) * 2048 + v_col;
  __bf16* kdst = &kt[w * 512];
  __bf16* vdst = &vt[w * 512];

  bf16x8 qf[2];
#pragma unroll
  for (int kk = 0; kk < 2; ++kk)
    qf[kk] = *(const bf16x8*)(qb + ((size_t)bh * 2048 + wq0 + lr) * 64 + kk * 32 + lg * 8);

  float mrun = -1e30f, lsum = 0.f;
  f32x4 apv[4] = {};

  for (int kv = 0; kv < ntiles; ++kv) {
    const int kv0 = kv * 128;
    __syncthreads();
#pragma unroll
    for (int i = 0; i < 4; ++i) {
      gll16(ksrc + (size_t)(kv0 + i * 32) * 64, kdst + i * 2048);
      gll16(vsrc + (size_t)i * 16 * 2048 + kv0, vdst + i * 2048);
    }
    __syncthreads();   // drains vmcnt -> tiles ready

    // ---- QK^T swapped (setprio around MFMA cluster) ----
    f32x4 sc[8] = {};
    __builtin_amdgcn_s_setprio(1);
#pragma unroll
    for (int kk = 0; kk < 2; ++kk)
#pragma unroll
      for (int nf = 0; nf < 8; ++nf) {
        bf16x8 kf = *(const bf16x8*)&kt[SWZK(nf * 16 + lr, kk * 32 + lg * 8)];
        sc[nf] = __builtin_amdgcn_mfma_f32_16x16x32_bf16(kf, qf[kk], sc[nf], 0, 0, 0);
      }
    __builtin_amdgcn_s_setprio(0);

    const int qrow = wq0 + lr;
    if (kv == ntiles - 1) {
#pragma unroll
      for (int nf = 0; nf < 8; ++nf)
#pragma unroll
        for (int r = 0; r < 4; ++r)
          if (kv0 + nf * 16 + lg * 4 + r > qrow) sc[nf][r] = -1e30f;
    }

    f32x4 m4 = sc[0];
#pragma unroll
    for (int nf = 1; nf < 8; ++nf)
#pragma unroll
      for (int r = 0; r < 4; ++r) m4[r] = fmaxf(m4[r], sc[nf][r]);
    float mx = fmaxf(fmaxf(m4[0], m4[1]), fmaxf(m4[2], m4[3]));
    mx = fmaxf(mx, __shfl_xor(mx, 16, 64));
    mx = fmaxf(mx, __shfl_xor(mx, 32, 64));

    if (!__all(mx - mrun <= DEFER_THR)) {
      float mold = mrun;
      float mn = fmaxf(mold, mx);
      mrun = mn;
      float scl = __builtin_amdgcn_exp2f(mold - mn);
      lsum *= scl;
      float sclq[4];
#pragma unroll
      for (int r = 0; r < 4; ++r) sclq[r] = __shfl(scl, (lg << 2) | r, 16);
#pragma unroll
      for (int nf = 0; nf < 4; ++nf)
#pragma unroll
        for (int r = 0; r < 4; ++r) apv[nf][r] *= sclq[r];
    }

    f32x4 rs4 = {0.f, 0.f, 0.f, 0.f};
#pragma unroll
    for (int nf = 0; nf < 8; ++nf)
#pragma unroll
      for (int r = 0; r < 4; ++r) {
        float pv = __builtin_amdgcn_exp2f(sc[nf][r] - mrun);
        sc[nf][r] = pv;
        rs4[r] += pv;
      }
    float rs = (rs4[0] + rs4[1]) + (rs4[2] + rs4[3]);
    rs += __shfl_xor(rs, 16, 64);
    rs += __shfl_xor(rs, 32, 64);
    lsum += rs;

    // ---- in-register P redistribution (pure VALU) + PV (setprio) ----
    __builtin_amdgcn_s_setprio(1);
#pragma unroll
    for (int kk = 0; kk < 4; ++kk) {
      uint32_t a0, a1, b0, b1;
      asm("v_cvt_pk_bf16_f32 %0, %1, %2" : "=v"(a0) : "v"(sc[2 * kk][0]), "v"(sc[2 * kk][1]));
      asm("v_cvt_pk_bf16_f32 %0, %1, %2" : "=v"(a1) : "v"(sc[2 * kk][2]), "v"(sc[2 * kk][3]));
      asm("v_cvt_pk_bf16_f32 %0, %1, %2" : "=v"(b0) : "v"(sc[2 * kk + 1][0]), "v"(sc[2 * kk + 1][1]));
      asm("v_cvt_pk_bf16_f32 %0, %1, %2" : "=v"(b1) : "v"(sc[2 * kk + 1][2]), "v"(sc[2 * kk + 1][3]));
      asm("v_permlane32_swap_b32 %0, %1" : "+v"(a0), "+v"(b0));
      asm("v_permlane32_swap_b32 %0, %1" : "+v"(a1), "+v"(b1));
      asm("v_permlane16_swap_b32 %0, %1" : "+v"(a0), "+v"(b0));
      asm("v_permlane16_swap_b32 %0, %1" : "+v"(a1), "+v"(b1));
      union { uint32_t u[4]; bf16x8 v; } pa;
      pa.u[0] = a0; pa.u[1] = a1; pa.u[2] = b0; pa.u[3] = b1;
#pragma unroll
      for (int nf = 0; nf < 4; ++nf) {
        bf16x8 vf = *(const bf16x8*)&vt[SWZ(nf * 16 + lr, kk * 32 + lg * 8)];
        apv[nf] = __builtin_amdgcn_mfma_f32_16x16x32_bf16(pa.v, vf, apv[nf], 0, 0, 0);
      }
    }
    __builtin_amdgcn_s_setprio(0);
  }

  // ---- memory retrieval ----
  __syncthreads();
  __bf16* mt = kt;
  for (int i = tid; i < 64 * 64; i += 256) {
    int d = i >> 6, e = i & 63;
    mt[e * 72 + d] = (__bf16)memory[((size_t)hh * 64 + d) * 64 + e];
  }
  for (int i = tid; i < 16 * 64; i += 256) {
    int e = 64 + (i >> 6), d = i & 63;
    mt[e * 72 + d] = (__bf16)memnorm[hh * 64 + d];
  }
  __syncthreads();

  bf16x8 sf[2];
#pragma unroll
  for (int kk = 0; kk < 2; ++kk) {
    bf16x8 q = qf[kk], s;
#pragma unroll
    for (int j = 0; j < 8; ++j) {
      float x = (float)q[j];
      float sg = x > 0.f ? x + 1.f : __builtin_amdgcn_exp2f(x * LOG2E);
      s[j] = (__bf16)sg;
    }
    sf[kk] = s;
  }

  f32x4 am[5] = {};
#pragma unroll
  for (int kk = 0; kk < 2; ++kk)
#pragma unroll
    for (int nf = 0; nf < 5; ++nf) {
      bf16x8 bb = *(const bf16x8*)&mt[(nf * 16 + lr) * 72 + kk * 32 + lg * 8];
      am[nf] = __builtin_amdgcn_mfma_f32_16x16x32_bf16(sf[kk], bb, am[nf], 0, 0, 0);
    }

  const float gate = 1.f / (1.f + __builtin_amdgcn_exp2f(-beta[hh] * LOG2E));
  const float og = 1.f - gate;
  float lsq[4];
#pragma unroll
  for (int r = 0; r < 4; ++r) lsq[r] = __shfl(lsum, (lg << 2) | r, 16);
#pragma unroll
  for (int r = 0; r < 4; ++r) {
    int row = wq0 + lg * 4 + r;
    float linv = __builtin_amdgcn_rcpf(lsq[r]);
    float nrm = fmaxf(am[4][r], 1e-6f);
    float ninv = __builtin_amdgcn_rcpf(nrm);
    size_t base = ((size_t)b * 2048 + row) * 1024 + hh * 64;
#pragma unroll
    for (int nf = 0; nf < 4; ++nf) {
      float al = apv[nf][r] * linv;
      float amv = am[nf][r] * ninv;
      comb[base + nf * 16 + lr] = (__bf16)(gate * amv + og * al);
    }
  }
}

// ---------------- launch ----------------
extern "C" void kernel_launch(void* const* d_in, const int* in_sizes, int n_in,
                              void* d_out, int out_size, void* d_ws, size_t ws_size,
                              hipStream_t stream) {
  const float* hs      = (const float*)d_in[0];
  const float* wq      = (const float*)d_in[1];
  const float* wk      = (const float*)d_in[2];
  const float* wv      = (const float*)d_in[3];
  const float* wo      = (const float*)d_in[4];
  const float* beta    = (const float*)d_in[5];
  const float* memory  = (const float*)d_in[6];
  const float* memnorm = (const float*)d_in[7];
  float* out = (float*)d_out;

  char* ws = (char*)d_ws;
  __bf16* hsb  = (__bf16*)(ws);                        // 8 MB  [4096][1024]
  __bf16* wqb  = (__bf16*)(ws + ((size_t)8  << 20));   // 2 MB
  __bf16* wkb  = (__bf16*)(ws + ((size_t)10 << 20));   // 2 MB
  __bf16* wvb  = (__bf16*)(ws + ((size_t)12 << 20));   // 2 MB
  __bf16* wob  = (__bf16*)(ws + ((size_t)14 << 20));   // 2 MB
  __bf16* qbuf = (__bf16*)(ws + ((size_t)16 << 20));   // 8 MB  [32][2048][64]
  __bf16* kbuf = (__bf16*)(ws + ((size_t)24 << 20));   // 8 MB
  __bf16* vtb  = (__bf16*)(ws + ((size_t)32 << 20));   // 8 MB  [32][64][2048]
  __bf16* comb = (__bf16*)(ws + ((size_t)40 << 20));   // 8 MB  [4096][1024]

  cvt_all<<<8192, 256, 0, stream>>>(hs, wq, wk, wv, wo, hsb, wqb, wkb, wvb, wob);

  qkv_gemm<<<768, 256, 0, stream>>>(hsb, wqb, wkb, wvb, qbuf, kbuf, vtb);

  attn_kernel<<<1024, 256, 0, stream>>>(qbuf, kbuf, vtb, memory, memnorm, beta, comb);

  gemm_out<<<dim3(32, 16), 256, 0, stream>>>(comb, wob, out, 4096, 1024);
}

// Round 13
// 97.093 us; speedup vs baseline: 1.2038x; 1.0376x over previous
//
#include <hip/hip_runtime.h>
#include <stdint.h>

#define LOG2E 1.4426950408889634f

typedef __attribute__((ext_vector_type(8))) __bf16 bf16x8;
typedef __attribute__((ext_vector_type(4))) __bf16 bf16x4;
typedef __attribute__((ext_vector_type(4))) float f32x4;

__device__ inline void gll16(const void* g, void* l) {
  __builtin_amdgcn_global_load_lds(
      (const __attribute__((address_space(1))) void*)g,
      (__attribute__((address_space(3))) void*)l, 16, 0, 0);
}

// ---------------- fp32 -> bf16 conversion (all 5 tensors, one launch) ----------------
__global__ __launch_bounds__(256) void cvt_all(
    const float* __restrict__ hs, const float* __restrict__ wq,
    const float* __restrict__ wk, const float* __restrict__ wv,
    const float* __restrict__ wo,
    __bf16* __restrict__ hsb, __bf16* __restrict__ wqb, __bf16* __restrict__ wkb,
    __bf16* __restrict__ wvb, __bf16* __restrict__ wob) {
  int bid = blockIdx.x;
  const float* s; __bf16* d; int i;
  if (bid < 4096) { s = hs; d = hsb; i = bid * 256 + threadIdx.x; }
  else {
    int seg = (bid - 4096) >> 10;
    i = ((bid - 4096) & 1023) * 256 + threadIdx.x;
    s = seg == 0 ? wq : seg == 1 ? wk : seg == 2 ? wv : wo;
    d = seg == 0 ? wqb : seg == 1 ? wkb : seg == 2 ? wvb : wob;
  }
  float4 v = ((const float4*)s)[i];
  bf16x4 o;
  o[0] = (__bf16)v.x; o[1] = (__bf16)v.y; o[2] = (__bf16)v.z; o[3] = (__bf16)v.w;
  *(bf16x4*)&d[(size_t)i * 4] = o;
}

// ---------------- merged QKV projection GEMM (BK=64, XOR-swizzled LDS) ----------------
#define KSCALE 0.18033688011112042f  // HD^-0.5 * log2(e)
#define QSWZ(row, col) (((row) << 6) + ((col) ^ (((row) & 7) << 3)))

__global__ __launch_bounds__(256, 3) void qkv_gemm(
    const __bf16* __restrict__ hsb, const __bf16* __restrict__ wqb,
    const __bf16* __restrict__ wkb, const __bf16* __restrict__ wvb,
    __bf16* __restrict__ qbuf, __bf16* __restrict__ kbuf,
    __bf16* __restrict__ vtb) {
  constexpr int K = 1024;
  __shared__ __align__(16) __bf16 lta[128 * 64];   // 16 KB
  __shared__ __align__(16) __bf16 ltb[128 * 64];   // 16 KB
  const int bid = blockIdx.x;
  const int z = bid >> 8, r = bid & 255;
  const __bf16 *A, *Bt;
  int m0, n0;
  if (z < 2) {
    A = hsb; Bt = z ? wkb : wqb;
    m0 = (r & 31) * 128; n0 = (r >> 5) * 128;
  } else {
    A = wvb; Bt = hsb;
    m0 = (r & 7) * 128; n0 = (r >> 3) * 128;
  }
  const int tid = threadIdx.x;
  const int w = tid >> 6, l = tid & 63;
  const int lg = l >> 4, lr = l & 15;
  const int wm = (w >> 1) * 64, wn = (w & 1) * 64;
  f32x4 acc[4][4] = {};
  const int srow = tid >> 3;                               // 0..31
  const int scol = ((tid & 7) ^ ((tid >> 3) & 7)) * 8;
  const __bf16* ga = A + (size_t)(m0 + srow) * K + scol;
  const __bf16* gb = Bt + (size_t)(n0 + srow) * K + scol;
  for (int k0 = 0; k0 < K; k0 += 64) {
    __syncthreads();
#pragma unroll
    for (int p = 0; p < 4; ++p) {
      gll16(ga + (size_t)p * 32 * K + k0, &lta[p * 2048 + w * 512]);
      gll16(gb + (size_t)p * 32 * K + k0, &ltb[p * 2048 + w * 512]);
    }
    __syncthreads();
#pragma unroll
    for (int kk = 0; kk < 2; ++kk) {
      bf16x8 af[4], bfr[4];
#pragma unroll
      for (int i = 0; i < 4; ++i) {
        af[i]  = *(const bf16x8*)&lta[QSWZ(wm + i * 16 + lr, kk * 32 + lg * 8)];
        bfr[i] = *(const bf16x8*)&ltb[QSWZ(wn + i * 16 + lr, kk * 32 + lg * 8)];
      }
#pragma unroll
      for (int i = 0; i < 4; ++i)
#pragma unroll
        for (int j = 0; j < 4; ++j)
          acc[i][j] = __builtin_amdgcn_mfma_f32_16x16x32_bf16(af[i], bfr[j], acc[i][j], 0, 0, 0);
    }
  }
#pragma unroll
  for (int i = 0; i < 4; ++i)
#pragma unroll
    for (int j = 0; j < 4; ++j)
#pragma unroll
      for (int rr = 0; rr < 4; ++rr) {
        int gm = m0 + wm + i * 16 + lg * 4 + rr;
        int gn = n0 + wn + j * 16 + lr;
        float v = acc[i][j][rr];
        if (z < 2) {
          int bb = gm >> 11, s = gm & 2047, hh = gn >> 6, d = gn & 63;
          __bf16* dst = z ? kbuf : qbuf;
          if (z) v *= KSCALE;
          dst[(((size_t)bb * 16 + hh) * 2048 + s) * 64 + d] = (__bf16)v;
        } else {
          int bb = gn >> 11, s = gn & 2047, hh = gm >> 6, d = gm & 63;
          vtb[(((size_t)bb * 16 + hh) * 64 + d) * 2048 + s] = (__bf16)v;
        }
      }
}

// ---------------- output GEMM: 128x64 tiles, BK=64, XOR-swizzled LDS ----------------
__global__ __launch_bounds__(256, 4) void gemm_out(const __bf16* __restrict__ A,
                                                   const __bf16* __restrict__ Bt,
                                                   float* __restrict__ C,
                                                   int M, int N) {
  constexpr int K = 1024;
  __shared__ __align__(16) __bf16 lta[128 * 64];   // 16 KB
  __shared__ __align__(16) __bf16 ltb[64 * 64];    // 8 KB
  const int tid = threadIdx.x;
  const int w = tid >> 6, l = tid & 63;
  const int lg = l >> 4, lr = l & 15;
  const int m0 = blockIdx.x * 128, n0 = blockIdx.y * 64;
  const int wm = (w >> 1) * 64, wn = (w & 1) * 32;
  f32x4 acc[4][2] = {};
  const int srow = tid >> 3;                               // 0..31
  const int scol = ((tid & 7) ^ ((tid >> 3) & 7)) * 8;
  const __bf16* ga = A + (size_t)(m0 + srow) * K + scol;
  const __bf16* gb = Bt + (size_t)(n0 + srow) * K + scol;
  for (int k0 = 0; k0 < K; k0 += 64) {
    __syncthreads();
#pragma unroll
    for (int p = 0; p < 4; ++p)
      gll16(ga + (size_t)p * 32 * K + k0, &lta[p * 2048 + w * 512]);
#pragma unroll
    for (int p = 0; p < 2; ++p)
      gll16(gb + (size_t)p * 32 * K + k0, &ltb[p * 2048 + w * 512]);
    __syncthreads();
#pragma unroll
    for (int kk = 0; kk < 2; ++kk) {
      bf16x8 af[4], bfr[2];
#pragma unroll
      for (int i = 0; i < 4; ++i)
        af[i]  = *(const bf16x8*)&lta[QSWZ(wm + i * 16 + lr, kk * 32 + lg * 8)];
#pragma unroll
      for (int j = 0; j < 2; ++j)
        bfr[j] = *(const bf16x8*)&ltb[QSWZ(wn + j * 16 + lr, kk * 32 + lg * 8)];
#pragma unroll
      for (int i = 0; i < 4; ++i)
#pragma unroll
        for (int j = 0; j < 2; ++j)
          acc[i][j] = __builtin_amdgcn_mfma_f32_16x16x32_bf16(af[i], bfr[j], acc[i][j], 0, 0, 0);
    }
  }
#pragma unroll
  for (int i = 0; i < 4; ++i)
#pragma unroll
    for (int j = 0; j < 2; ++j)
#pragma unroll
      for (int rr = 0; rr < 4; ++rr) {
        int gm = m0 + wm + i * 16 + lg * 4 + rr;
        int gn = n0 + wn + j * 16 + lr;
        C[(size_t)gm * N + gn] = acc[i][j][rr];
      }
}

// ---------------- attention + memory retrieval (split-drain) ----------------
// R12 structure; per-iter: issue kt then vt gll16; vmcnt(4)+barrier -> QK^T
// runs while vt lands; vmcnt(0)+barrier -> PV. vt drain hides under softmax.
#define DEFER_THR 11.5f
#define SWZ(row, col) (((row) << 7) + ((col) ^ (((row) & 7) << 3)))   // stride 128
#define SWZK(row, col) (((row) << 6) + ((col) ^ (((row) & 7) << 3)))  // stride 64

__global__ __launch_bounds__(256, 5) void attn_kernel(
    const __bf16* __restrict__ qb,    // [32][2048][64]
    const __bf16* __restrict__ kb,    // [32][2048][64] (pre-scaled)
    const __bf16* __restrict__ vtb,   // [32][64][2048]
    const float* __restrict__ memory, // [16][64][64]
    const float* __restrict__ memnorm,// [16][64]
    const float* __restrict__ beta,   // [16]
    __bf16* __restrict__ comb)        // [4096][1024]
{
  __shared__ __align__(16) __bf16 kt[128 * 64];   // 16 KB (reused as mt)
  __shared__ __align__(16) __bf16 vt[64 * 128];   // 16 KB  -> 32 KB total

  const int tid = threadIdx.x;
  const int w = tid >> 6, l = tid & 63;
  const int lg = l >> 4, lr = l & 15;
  const int t = 31 - (blockIdx.x >> 5);
  const int bh = blockIdx.x & 31;
  const int hh = bh & 15, b = bh >> 4;
  const int wq0 = t * 64 + w * 16;
  const int ntiles = (t >> 1) + 1;

  const int k_row = tid >> 3;                          // 0..31
  const int k_col = ((tid & 7) ^ (k_row & 7)) * 8;
  const __bf16* ksrc = kb + ((size_t)bh * 2048 + k_row) * 64 + k_col;
  const int v_d = tid >> 4;                            // 0..15
  const int v_col = ((tid & 15) ^ (v_d & 7)) * 8;
  const __bf16* vsrc = vtb + ((size_t)bh * 64 + v_d) * 2048 + v_col;
  __bf16* kdst = &kt[w * 512];
  __bf16* vdst = &vt[w * 512];

  bf16x8 qf[2];
#pragma unroll
  for (int kk = 0; kk < 2; ++kk)
    qf[kk] = *(const bf16x8*)(qb + ((size_t)bh * 2048 + wq0 + lr) * 64 + kk * 32 + lg * 8);

  float mrun = -1e30f, lsum = 0.f;
  f32x4 apv[4] = {};

  for (int kv = 0; kv < ntiles; ++kv) {
    const int kv0 = kv * 128;
    __syncthreads();    // previous iter's kt/vt reads complete everywhere
    // issue kt FIRST (oldest 4 vmem ops), then vt
#pragma unroll
    for (int i = 0; i < 4; ++i)
      gll16(ksrc + (size_t)(kv0 + i * 32) * 64, kdst + i * 2048);
#pragma unroll
    for (int i = 0; i < 4; ++i)
      gll16(vsrc + (size_t)i * 16 * 2048 + kv0, vdst + i * 2048);
    asm volatile("s_waitcnt vmcnt(4)" ::: "memory");   // own kt done
    __builtin_amdgcn_sched_barrier(0);
    __builtin_amdgcn_s_barrier();                      // => ALL kt done

    // ---- QK^T swapped (kt only) ----
    f32x4 sc[8] = {};
    __builtin_amdgcn_s_setprio(1);
#pragma unroll
    for (int kk = 0; kk < 2; ++kk)
#pragma unroll
      for (int nf = 0; nf < 8; ++nf) {
        bf16x8 kf = *(const bf16x8*)&kt[SWZK(nf * 16 + lr, kk * 32 + lg * 8)];
        sc[nf] = __builtin_amdgcn_mfma_f32_16x16x32_bf16(kf, qf[kk], sc[nf], 0, 0, 0);
      }
    __builtin_amdgcn_s_setprio(0);

    const int qrow = wq0 + lr;
    if (kv == ntiles - 1) {
#pragma unroll
      for (int nf = 0; nf < 8; ++nf)
#pragma unroll
        for (int r = 0; r < 4; ++r)
          if (kv0 + nf * 16 + lg * 4 + r > qrow) sc[nf][r] = -1e30f;
    }

    f32x4 m4 = sc[0];
#pragma unroll
    for (int nf = 1; nf < 8; ++nf)
#pragma unroll
      for (int r = 0; r < 4; ++r) m4[r] = fmaxf(m4[r], sc[nf][r]);
    float mx = fmaxf(fmaxf(m4[0], m4[1]), fmaxf(m4[2], m4[3]));
    mx = fmaxf(mx, __shfl_xor(mx, 16, 64));
    mx = fmaxf(mx, __shfl_xor(mx, 32, 64));

    if (!__all(mx - mrun <= DEFER_THR)) {
      float mold = mrun;
      float mn = fmaxf(mold, mx);
      mrun = mn;
      float scl = __builtin_amdgcn_exp2f(mold - mn);
      lsum *= scl;
      float sclq[4];
#pragma unroll
      for (int r = 0; r < 4; ++r) sclq[r] = __shfl(scl, (lg << 2) | r, 16);
#pragma unroll
      for (int nf = 0; nf < 4; ++nf)
#pragma unroll
        for (int r = 0; r < 4; ++r) apv[nf][r] *= sclq[r];
    }

    f32x4 rs4 = {0.f, 0.f, 0.f, 0.f};
#pragma unroll
    for (int nf = 0; nf < 8; ++nf)
#pragma unroll
      for (int r = 0; r < 4; ++r) {
        float pv = __builtin_amdgcn_exp2f(sc[nf][r] - mrun);
        sc[nf][r] = pv;
        rs4[r] += pv;
      }
    float rs = (rs4[0] + rs4[1]) + (rs4[2] + rs4[3]);
    rs += __shfl_xor(rs, 16, 64);
    rs += __shfl_xor(rs, 32, 64);
    lsum += rs;

    asm volatile("s_waitcnt vmcnt(0)" ::: "memory");   // own vt done
    __builtin_amdgcn_sched_barrier(0);
    __builtin_amdgcn_s_barrier();                      // => ALL vt done

    // ---- in-register P redistribution (pure VALU) + PV ----
    __builtin_amdgcn_s_setprio(1);
#pragma unroll
    for (int kk = 0; kk < 4; ++kk) {
      uint32_t a0, a1, b0, b1;
      asm("v_cvt_pk_bf16_f32 %0, %1, %2" : "=v"(a0) : "v"(sc[2 * kk][0]), "v"(sc[2 * kk][1]));
      asm("v_cvt_pk_bf16_f32 %0, %1, %2" : "=v"(a1) : "v"(sc[2 * kk][2]), "v"(sc[2 * kk][3]));
      asm("v_cvt_pk_bf16_f32 %0, %1, %2" : "=v"(b0) : "v"(sc[2 * kk + 1][0]), "v"(sc[2 * kk + 1][1]));
      asm("v_cvt_pk_bf16_f32 %0, %1, %2" : "=v"(b1) : "v"(sc[2 * kk + 1][2]), "v"(sc[2 * kk + 1][3]));
      asm("v_permlane32_swap_b32 %0, %1" : "+v"(a0), "+v"(b0));
      asm("v_permlane32_swap_b32 %0, %1" : "+v"(a1), "+v"(b1));
      asm("v_permlane16_swap_b32 %0, %1" : "+v"(a0), "+v"(b0));
      asm("v_permlane16_swap_b32 %0, %1" : "+v"(a1), "+v"(b1));
      union { uint32_t u[4]; bf16x8 v; } pa;
      pa.u[0] = a0; pa.u[1] = a1; pa.u[2] = b0; pa.u[3] = b1;
#pragma unroll
      for (int nf = 0; nf < 4; ++nf) {
        bf16x8 vf = *(const bf16x8*)&vt[SWZ(nf * 16 + lr, kk * 32 + lg * 8)];
        apv[nf] = __builtin_amdgcn_mfma_f32_16x16x32_bf16(pa.v, vf, apv[nf], 0, 0, 0);
      }
    }
    __builtin_amdgcn_s_setprio(0);
  }

  // ---- memory retrieval ----
  __syncthreads();
  __bf16* mt = kt;
  for (int i = tid; i < 64 * 64; i += 256) {
    int d = i >> 6, e = i & 63;
    mt[e * 72 + d] = (__bf16)memory[((size_t)hh * 64 + d) * 64 + e];
  }
  for (int i = tid; i < 16 * 64; i += 256) {
    int e = 64 + (i >> 6), d = i & 63;
    mt[e * 72 + d] = (__bf16)memnorm[hh * 64 + d];
  }
  __syncthreads();

  bf16x8 sf[2];
#pragma unroll
  for (int kk = 0; kk < 2; ++kk) {
    bf16x8 q = qf[kk], s;
#pragma unroll
    for (int j = 0; j < 8; ++j) {
      float x = (float)q[j];
      float sg = x > 0.f ? x + 1.f : __builtin_amdgcn_exp2f(x * LOG2E);
      s[j] = (__bf16)sg;
    }
    sf[kk] = s;
  }

  f32x4 am[5] = {};
#pragma unroll
  for (int kk = 0; kk < 2; ++kk)
#pragma unroll
    for (int nf = 0; nf < 5; ++nf) {
      bf16x8 bb = *(const bf16x8*)&mt[(nf * 16 + lr) * 72 + kk * 32 + lg * 8];
      am[nf] = __builtin_amdgcn_mfma_f32_16x16x32_bf16(sf[kk], bb, am[nf], 0, 0, 0);
    }

  const float gate = 1.f / (1.f + __builtin_amdgcn_exp2f(-beta[hh] * LOG2E));
  const float og = 1.f - gate;
  float lsq[4];
#pragma unroll
  for (int r = 0; r < 4; ++r) lsq[r] = __shfl(lsum, (lg << 2) | r, 16);
#pragma unroll
  for (int r = 0; r < 4; ++r) {
    int row = wq0 + lg * 4 + r;
    float linv = __builtin_amdgcn_rcpf(lsq[r]);
    float nrm = fmaxf(am[4][r], 1e-6f);
    float ninv = __builtin_amdgcn_rcpf(nrm);
    size_t base = ((size_t)b * 2048 + row) * 1024 + hh * 64;
#pragma unroll
    for (int nf = 0; nf < 4; ++nf) {
      float al = apv[nf][r] * linv;
      float amv = am[nf][r] * ninv;
      comb[base + nf * 16 + lr] = (__bf16)(gate * amv + og * al);
    }
  }
}

// ---------------- launch ----------------
extern "C" void kernel_launch(void* const* d_in, const int* in_sizes, int n_in,
                              void* d_out, int out_size, void* d_ws, size_t ws_size,
                              hipStream_t stream) {
  const float* hs      = (const float*)d_in[0];
  const float* wq      = (const float*)d_in[1];
  const float* wk      = (const float*)d_in[2];
  const float* wv      = (const float*)d_in[3];
  const float* wo      = (const float*)d_in[4];
  const float* beta    = (const float*)d_in[5];
  const float* memory  = (const float*)d_in[6];
  const float* memnorm = (const float*)d_in[7];
  float* out = (float*)d_out;

  char* ws = (char*)d_ws;
  __bf16* hsb  = (__bf16*)(ws);                        // 8 MB  [4096][1024]
  __bf16* wqb  = (__bf16*)(ws + ((size_t)8  << 20));   // 2 MB
  __bf16* wkb  = (__bf16*)(ws + ((size_t)10 << 20));   // 2 MB
  __bf16* wvb  = (__bf16*)(ws + ((size_t)12 << 20));   // 2 MB
  __bf16* wob  = (__bf16*)(ws + ((size_t)14 << 20));   // 2 MB
  __bf16* qbuf = (__bf16*)(ws + ((size_t)16 << 20));   // 8 MB  [32][2048][64]
  __bf16* kbuf = (__bf16*)(ws + ((size_t)24 << 20));   // 8 MB
  __bf16* vtb  = (__bf16*)(ws + ((size_t)32 << 20));   // 8 MB  [32][64][2048]
  __bf16* comb = (__bf16*)(ws + ((size_t)40 << 20));   // 8 MB  [4096][1024]

  cvt_all<<<8192, 256, 0, stream>>>(hs, wq, wk, wv, wo, hsb, wqb, wkb, wvb, wob);

  qkv_gemm<<<768, 256, 0, stream>>>(hsb, wqb, wkb, wvb, qbuf, kbuf, vtb);

  attn_kernel<<<1024, 256, 0, stream>>>(qbuf, kbuf, vtb, memory, memnorm, beta, comb);

  gemm_out<<<dim3(32, 16), 256, 0, stream>>>(comb, wob, out, 4096, 1024);
}